// Round 8
// baseline (181.854 us; speedup 1.0000x reference)
//
#include <hip/hip_runtime.h>
#include <hip/hip_bf16.h>

#define B_ 8
#define L_ 4096
#define C_ 256
#define H_ 8
#define D_ 32
#define CHUNK_ 128
#define NC_ 32
#define M_ (B_*L_)   // 32768

typedef _Float16 f16x8 __attribute__((ext_vector_type(8)));
typedef _Float16 f16x4 __attribute__((ext_vector_type(4)));
typedef float    f32x4 __attribute__((ext_vector_type(4)));

#define GLOAD_LDS16(g, l) __builtin_amdgcn_global_load_lds( \
    (const __attribute__((address_space(1))) unsigned int*)(g), \
    (__attribute__((address_space(3))) unsigned int*)(l), 16, 0, 0)

// ---------------------------------------------------------------------------
// Prep: h = f16(x + rel_pos)  and  weights -> f16   (one launch)
// ---------------------------------------------------------------------------
__global__ __launch_bounds__(256) void k_prep(
    const float* __restrict__ x, const float* __restrict__ rel,
    const float* __restrict__ qw, const float* __restrict__ pw,
    _Float16* __restrict__ h, _Float16* __restrict__ qwb, _Float16* __restrict__ pwb)
{
    const int bx = blockIdx.x;
    if (bx < 4096) {
        const int i = (bx * 256 + threadIdx.x) * 8;
        float4 x0 = *(const float4*)(x + i);
        float4 x1 = *(const float4*)(x + i + 4);
        const int ri = i & (L_ * C_ - 1);
        float4 r0 = *(const float4*)(rel + ri);
        float4 r1 = *(const float4*)(rel + ri + 4);
        f16x8 o = { (_Float16)(x0.x + r0.x), (_Float16)(x0.y + r0.y),
                    (_Float16)(x0.z + r0.z), (_Float16)(x0.w + r0.w),
                    (_Float16)(x1.x + r1.x), (_Float16)(x1.y + r1.y),
                    (_Float16)(x1.z + r1.z), (_Float16)(x1.w + r1.w) };
        *(f16x8*)(h + i) = o;
    } else {
        const int i = ((bx - 4096) * 256 + threadIdx.x) * 4;
        const float* src; _Float16* dst; int off;
        if (i < 768 * 256) { src = qw; dst = qwb; off = i; }
        else               { src = pw; dst = pwb; off = i - 768 * 256; }
        float4 v = *(const float4*)(src + off);
        f16x4 o = { (_Float16)v.x, (_Float16)v.y, (_Float16)v.z, (_Float16)v.w };
        *(f16x4*)(dst + off) = o;
    }
}

// ---------------------------------------------------------------------------
// qkv GEMM, m97-style, XCD-swizzled 1D grid (1536 blocks). Epilogue fuses
// RMS-norm (Q/K) and the V transpose, staged in TWO 64-row passes through a
// half-size Ws (17408 B) so LDS block = 17 KB -> ~6 blocks/CU resident.
// ---------------------------------------------------------------------------
__global__ __launch_bounds__(256) void k_qkv_gemm(
    const _Float16* __restrict__ A, const _Float16* __restrict__ Bw,
    const float* __restrict__ qg, const float* __restrict__ kg,
    _Float16* __restrict__ Qg, _Float16* __restrict__ Kg, _Float16* __restrict__ Vtg)
{
    __shared__ __align__(16) char smem[17408];      // max(As+Bs=16K, Ws=17408)
    _Float16* As = (_Float16*)smem;                 // [128][32]
    _Float16* Bs = As + 128 * 32;                   // [128][32]
    _Float16* Ws = (_Float16*)smem;                 // epilogue half staging

    const int blk = blockIdx.x;
    const int xcd = blk & 7;
    const int t   = blk >> 3;                       // 0..191
    const int by  = xcd * 32 + (t & 31);
    const int bx  = t >> 5;                         // 0..5
    const int m0 = by * 128;
    const int n0 = bx * 128;

    const int tid = threadIdx.x;
    const int wv = tid >> 6, ln = tid & 63;
    const int lr = ln >> 2, lc = (ln & 3) * 8;
    const int wm = (wv >> 1) * 64, wn = (wv & 1) * 64;
    const int fr = ln & 15, fk = (ln >> 4) * 8;

    f32x4 acc[4][4] = {};
    const _Float16* ga = A  + (size_t)(m0 + wv * 16 + lr) * 256 + lc;
    const _Float16* gb = Bw + (size_t)(n0 + wv * 16 + lr) * 256 + lc;

    for (int k0 = 0; k0 < 256; k0 += 32) {
        GLOAD_LDS16(ga + k0,            As + (wv * 16) * 32);
        GLOAD_LDS16(ga + k0 + 64 * 256, As + (64 + wv * 16) * 32);
        GLOAD_LDS16(gb + k0,            Bs + (wv * 16) * 32);
        GLOAD_LDS16(gb + k0 + 64 * 256, Bs + (64 + wv * 16) * 32);
        __syncthreads();
        f16x8 af[4], bf[4];
#pragma unroll
        for (int i = 0; i < 4; ++i)
            af[i] = *(const f16x8*)(As + (wm + i * 16 + fr) * 32 + fk);
#pragma unroll
        for (int j = 0; j < 4; ++j)
            bf[j] = *(const f16x8*)(Bs + (wn + j * 16 + fr) * 32 + fk);
#pragma unroll
        for (int i = 0; i < 4; ++i)
#pragma unroll
            for (int j = 0; j < 4; ++j)
                acc[i][j] = __builtin_amdgcn_mfma_f32_16x16x32_f16(
                    af[i], bf[j], acc[i][j], 0, 0, 0);
        __syncthreads();
    }

    const int cr = (ln >> 4) * 4, cc = ln & 15;
    const int kind = n0 >> 8;                 // 0=Q 1=K 2=V
    const int col0 = (n0 & 255) + wn;
    const int bb = m0 >> 12, l00 = m0 & 4095;
    const int hbase = (n0 & 255) >> 5;
    const int myp = wv >> 1;                  // this wave's row-half

    if (kind < 2) {
        // fused RMS-norm (q's D^-1/2 pre-scale cancels; scale-invariant)
        const float* gsrc = kind ? kg : qg;
        _Float16* P = kind ? Kg : Qg;
        float gma[2][2];
#pragma unroll
        for (int jp = 0; jp < 2; ++jp)
#pragma unroll
            for (int jj = 0; jj < 2; ++jj)
                gma[jp][jj] = gsrc[((col0 >> 5) + jp) * 32 + jj * 16 + cc];
#pragma unroll
        for (int p = 0; p < 2; ++p) {
            if (myp == p) {
#pragma unroll
                for (int i = 0; i < 4; ++i)
#pragma unroll
                    for (int r = 0; r < 4; ++r) {
                        const int lrow = i * 16 + cr + r;      // 0..63
#pragma unroll
                        for (int jp = 0; jp < 2; ++jp) {
                            const float a0 = acc[i][jp * 2][r];
                            const float a1 = acc[i][jp * 2 + 1][r];
                            float ss = a0 * a0 + a1 * a1;
                            ss += __shfl_xor(ss, 1);
                            ss += __shfl_xor(ss, 2);
                            ss += __shfl_xor(ss, 4);
                            ss += __shfl_xor(ss, 8);
                            const float sc = 5.656854249492381f / fmaxf(sqrtf(ss), 1e-12f);
                            Ws[lrow * 136 + wn + jp * 32 + cc]      = (_Float16)(a0 * sc * gma[jp][0]);
                            Ws[lrow * 136 + wn + jp * 32 + 16 + cc] = (_Float16)(a1 * sc * gma[jp][1]);
                        }
                    }
            }
            __syncthreads();
#pragma unroll
            for (int kk = 0; kk < 4; ++kk) {
                const int c = kk * 256 + tid;         // 0..1023 f16x8 chunks
                const int hh = c >> 8;                // head within tile
                const int rr = (c >> 2) & 63;         // local row
                const int part = (c & 3) * 8;
                f16x8 v8 = *(const f16x8*)(Ws + rr * 136 + hh * 32 + part);
                *(f16x8*)(P + ((size_t)(bb * 8 + hbase + hh) * 4096 + l00 + p * 64 + rr) * 32 + part) = v8;
            }
            __syncthreads();
        }
    } else {
        // V: transpose through half-LDS (2 passes of 64 rows) -> [bh][e][4096]
#pragma unroll
        for (int p = 0; p < 2; ++p) {
            if (myp == p) {
#pragma unroll
                for (int i = 0; i < 4; ++i)
#pragma unroll
                    for (int j = 0; j < 4; ++j) {
                        const int colL = wn + j * 16 + cc;    // 0..127
                        const int row0 = i * 16 + cr;         // local, 4-aligned
                        f16x4 v4 = { (_Float16)acc[i][j][0], (_Float16)acc[i][j][1],
                                     (_Float16)acc[i][j][2], (_Float16)acc[i][j][3] };
                        *(f16x4*)(Ws + colL * 68 + row0) = v4;
                    }
            }
            __syncthreads();
#pragma unroll
            for (int kk = 0; kk < 4; ++kk) {
                const int q = kk * 256 + tid;         // 0..1023
                const int c = q >> 3;                 // col 0..127
                const int seg = q & 7;                // 8-row segment
                const int col = (n0 & 255) + c;
                const int hh = col >> 5, e = col & 31;
                f16x8 v8 = *(const f16x8*)(Ws + c * 68 + seg * 8);
                *(f16x8*)(Vtg + ((size_t)(bb * 8 + hh) * 32 + e) * 4096 + l00 + p * 64 + seg * 8) = v8;
            }
            __syncthreads();
        }
    }
}

// ---------------------------------------------------------------------------
// Per-chunk KV outer product via MFMA: one wave per chunk.
// KV^T[e][d] = sum_pos V[pos][e] * K[pos][d] * exp(-s*(128-pos)).
// ---------------------------------------------------------------------------
__global__ __launch_bounds__(64) void k_chunk_kv(
    const _Float16* __restrict__ Kg, const _Float16* __restrict__ Vtg,
    float* __restrict__ kvbuf)
{
    __shared__ _Float16 Vp[32 * 136];   // [e][pos]
    __shared__ _Float16 Kp[32 * 136];   // [d][pos]
    const int blk = blockIdx.x;
    const int n  = blk & 31;
    const int bh = blk >> 5;
    const int h  = bh & 7;
    const float sl2 = exp2f(-(float)(h + 1)) * 1.44269504f;
    const int ln = threadIdx.x;
    const _Float16* Kc = Kg  + ((size_t)bh * 4096 + n * CHUNK_) * 32;
    const _Float16* Vc = Vtg + (size_t)bh * 32 * 4096 + n * CHUNK_;
#pragma unroll
    for (int i = 0; i < 8; ++i) {
        const int flat = i * 64 + ln;          // 0..511
        const int e = flat >> 4, seg = flat & 15;
        f16x8 v8 = *(const f16x8*)(Vc + (size_t)e * 4096 + seg * 8);
        *(f16x8*)(Vp + e * 136 + seg * 8) = v8;
        const int pos = flat >> 2, d0 = (flat & 3) * 8;
        f16x8 k8 = *(const f16x8*)(Kc + flat * 8);
#pragma unroll
        for (int j = 0; j < 8; ++j) Kp[(d0 + j) * 136 + pos] = k8[j];
    }
    __syncthreads();
    const int fr = ln & 15, fk = (ln >> 4) * 8;
    const float r = exp2f(sl2);
    float rj[8];
    rj[0] = 1.f;
#pragma unroll
    for (int j = 1; j < 8; ++j) rj[j] = rj[j - 1] * r;
    f32x4 acc[2][2] = {};
    for (int k0 = 0; k0 < 128; k0 += 32) {
        const float e0 = exp2f(-sl2 * (float)(CHUNK_ - (k0 + fk)));
        f16x8 av[2], bd[2];
#pragma unroll
        for (int i = 0; i < 2; ++i)
            av[i] = *(const f16x8*)(Vp + (i * 16 + fr) * 136 + k0 + fk);
#pragma unroll
        for (int jt = 0; jt < 2; ++jt) {
            f16x8 kraw = *(const f16x8*)(Kp + (jt * 16 + fr) * 136 + k0 + fk);
            f16x8 kb;
#pragma unroll
            for (int j = 0; j < 8; ++j)
                kb[j] = (_Float16)((float)kraw[j] * (e0 * rj[j]));
            bd[jt] = kb;
        }
#pragma unroll
        for (int i = 0; i < 2; ++i)
#pragma unroll
            for (int jt = 0; jt < 2; ++jt)
                acc[i][jt] = __builtin_amdgcn_mfma_f32_16x16x32_f16(
                    av[i], bd[jt], acc[i][jt], 0, 0, 0);
    }
    const int cr = (ln >> 4) * 4, cc = ln & 15;
    float* outp = kvbuf + (size_t)blk * 1024;
#pragma unroll
    for (int i = 0; i < 2; ++i)
#pragma unroll
        for (int jt = 0; jt < 2; ++jt)
#pragma unroll
            for (int rr = 0; rr < 4; ++rr)
                outp[(i * 16 + cr + rr) * 32 + jt * 16 + cc] = acc[i][jt][rr];
}

// ---------------------------------------------------------------------------
// Chunk-state scan, batched prefetch.
// ---------------------------------------------------------------------------
__global__ __launch_bounds__(256) void k_scan(float* __restrict__ kvbuf)
{
    const int bh = blockIdx.x;
    const int tid = threadIdx.x;
    const float slope = exp2f(-(float)((bh & 7) + 1));
    const float bd = __expf(-slope * (float)CHUNK_);
    float4 st = {0.f, 0.f, 0.f, 0.f};
    float4* base = (float4*)(kvbuf + (size_t)bh * NC_ * 1024) + tid;
#pragma unroll
    for (int g = 0; g < 4; ++g) {
        float4 tmp[8];
#pragma unroll
        for (int k = 0; k < 8; ++k) tmp[k] = base[(g * 8 + k) * 256];
#pragma unroll
        for (int k = 0; k < 8; ++k) {
            base[(g * 8 + k) * 256] = st;
            st.x = bd * st.x + tmp[k].x;
            st.y = bd * st.y + tmp[k].y;
            st.z = bd * st.z + tmp[k].z;
            st.w = bd * st.w + tmp[k].w;
        }
    }
}

// ---------------------------------------------------------------------------
// MFMA attention, low-LDS: Q/K/V fragments direct from global; only S̃ (and
// the small KV state) round-trip LDS. Os staging aliases Ss (barrier-guarded).
// ---------------------------------------------------------------------------
__global__ __launch_bounds__(256) void k_attn(
    const _Float16* __restrict__ Qg, const _Float16* __restrict__ Kg,
    const _Float16* __restrict__ Vtg, const float* __restrict__ kvbuf,
    _Float16* __restrict__ attnp)
{
    __shared__ __align__(16) _Float16 Ss[128 * 136];  // also Os[128][40] alias
    __shared__ __align__(16) _Float16 KVt[32 * 40];
    __shared__ float ejs[CHUNK_];
    _Float16* Os = Ss;
    const int blk = blockIdx.x;
    const int n  = blk & 31;
    const int bh = blk >> 5;
    const int h  = bh & 7;
    const float sl2 = exp2f(-(float)(h + 1)) * 1.44269504f;
    const int tid = threadIdx.x;
    const int wv = tid >> 6, ln = tid & 63;
    const int fr = ln & 15, fk = (ln >> 4) * 8;
    const int cr = (ln >> 4) * 4, cc = ln & 15;

    const _Float16* Qc = Qg + ((size_t)bh * 4096 + n * CHUNK_) * 32;
    const _Float16* Kc = Kg + ((size_t)bh * 4096 + n * CHUNK_) * 32;
    const _Float16* Vc = Vtg + (size_t)bh * 32 * 4096 + n * CHUNK_;

    {
        const float* kvp = kvbuf + (size_t)blk * 1024;
        f32x4 kv4f = *(const f32x4*)(kvp + tid * 4);
        f16x4 kv4 = { (_Float16)kv4f[0], (_Float16)kv4f[1],
                      (_Float16)kv4f[2], (_Float16)kv4f[3] };
        *(f16x4*)(KVt + (tid >> 3) * 40 + (tid & 7) * 4) = kv4;
    }
    if (tid < CHUNK_) ejs[tid] = exp2f(sl2 * (float)tid);
    __syncthreads();

    f16x8 aq[2];
#pragma unroll
    for (int i = 0; i < 2; ++i)
        aq[i] = *(const f16x8*)(Qc + (wv * 32 + i * 16 + fr) * 32 + fk);

    f32x4 sacc[2][8] = {};
#pragma unroll
    for (int j = 0; j < 8; ++j) {
        f16x8 bk = *(const f16x8*)(Kc + (j * 16 + fr) * 32 + fk);
#pragma unroll
        for (int i = 0; i < 2; ++i)
            sacc[i][j] = __builtin_amdgcn_mfma_f32_16x16x32_f16(aq[i], bk, sacc[i][j], 0, 0, 0);
    }
    f32x4 iacc[2][2] = {};
#pragma unroll
    for (int ct = 0; ct < 2; ++ct) {
        f16x8 bkv = *(const f16x8*)(KVt + (ct * 16 + fr) * 40 + fk);
#pragma unroll
        for (int i = 0; i < 2; ++i)
            iacc[i][ct] = __builtin_amdgcn_mfma_f32_16x16x32_f16(aq[i], bkv, iacc[i][ct], 0, 0, 0);
    }
    float ejr[8];
#pragma unroll
    for (int j = 0; j < 8; ++j) ejr[j] = ejs[j * 16 + cc];
    const float c1 = exp2f(-sl2);
    float qd_save[2][4];
#pragma unroll
    for (int i = 0; i < 2; ++i) {
        float er = exp2f(-sl2 * (float)(wv * 32 + i * 16 + cr));
#pragma unroll
        for (int r = 0; r < 4; ++r) {
            const int irow = wv * 32 + i * 16 + cr + r;
            qd_save[i][r] = er;
#pragma unroll
            for (int j = 0; j < 8; ++j) {
                const int jcol = j * 16 + cc;
                const float w = (jcol <= irow) ? ejr[j] * er : 0.f;
                Ss[irow * 136 + jcol] = (_Float16)(sacc[i][j][r] * w);
            }
            er *= c1;
        }
    }
    __syncthreads();

    f32x4 oacc[2][2] = {};
#pragma unroll
    for (int k = 0; k < 4; ++k) {
        f16x8 as[2], bv[2];
#pragma unroll
        for (int i = 0; i < 2; ++i)
            as[i] = *(const f16x8*)(Ss + (wv * 32 + i * 16 + fr) * 136 + k * 32 + fk);
#pragma unroll
        for (int ct = 0; ct < 2; ++ct)
            bv[ct] = *(const f16x8*)(Vc + (size_t)(ct * 16 + fr) * 4096 + k * 32 + fk);
#pragma unroll
        for (int i = 0; i < 2; ++i)
#pragma unroll
            for (int ct = 0; ct < 2; ++ct)
                oacc[i][ct] = __builtin_amdgcn_mfma_f32_16x16x32_f16(as[i], bv[ct], oacc[i][ct], 0, 0, 0);
    }
    __syncthreads();   // all Ss reads complete before Os (alias) is written
#pragma unroll
    for (int i = 0; i < 2; ++i)
#pragma unroll
        for (int r = 0; r < 4; ++r) {
            const int irow = wv * 32 + i * 16 + cr + r;
            const float qd = qd_save[i][r];
            Os[irow * 40 + cc]      = (_Float16)(oacc[i][0][r] + qd * iacc[i][0][r]);
            Os[irow * 40 + 16 + cc] = (_Float16)(oacc[i][1][r] + qd * iacc[i][1][r]);
        }
    __syncthreads();
    _Float16* abase = attnp + ((size_t)bh * 4096 + n * CHUNK_) * 32;
#pragma unroll
    for (int kk = 0; kk < 2; ++kk) {
        const int c = kk * 256 + tid;
        const int rr = c >> 2;
        const int part = (c & 3) * 8;
        *(f16x8*)(abase + rr * 32 + part) = *(const f16x8*)(Os + rr * 40 + part);
    }
}

// ---------------------------------------------------------------------------
// proj GEMM: out = attn @ proj_w^T + b, A from packed [bh][l][32].
// XCD-swizzled 1D grid (512 blocks).
// ---------------------------------------------------------------------------
__global__ __launch_bounds__(256) void k_proj_gemm(
    const _Float16* __restrict__ attnp, const _Float16* __restrict__ Bw,
    const float* __restrict__ bias, float* __restrict__ Cc)
{
    __shared__ _Float16 As[128 * 32];
    __shared__ _Float16 Bs[128 * 32];
    const int blk = blockIdx.x;
    const int xcd = blk & 7;
    const int t   = blk >> 3;                       // 0..63
    const int m0 = (xcd * 32 + (t & 31)) * 128;
    const int n0 = (t >> 5) * 128;

    const int tid = threadIdx.x;
    const int wv = tid >> 6, ln = tid & 63;
    const int lr = ln >> 2;
    const int lc = (ln & 3) * 8;
    const int wm = (wv >> 1) * 64;
    const int wn = (wv & 1) * 64;
    const int fr = ln & 15;
    const int fk = (ln >> 4) * 8;

    f32x4 acc[4][4] = {};
    const int gmrow = m0 + wv * 16 + lr;
    const _Float16* ga = attnp +
        ((size_t)(gmrow >> 12) * 8 * 4096 + (gmrow & 4095)) * 32 + lc;
    const _Float16* gb = Bw + (size_t)(n0 + wv * 16 + lr) * 256 + lc;

    for (int k0 = 0; k0 < 256; k0 += 32) {
        const size_t hoff = (size_t)(k0 >> 5) * (4096 * 32);
        GLOAD_LDS16(ga + hoff,           As + (wv * 16) * 32);
        GLOAD_LDS16(ga + hoff + 64 * 32, As + (64 + wv * 16) * 32);
        GLOAD_LDS16(gb + k0,             Bs + (wv * 16) * 32);
        GLOAD_LDS16(gb + k0 + 64 * 256,  Bs + (64 + wv * 16) * 32);
        __syncthreads();
        f16x8 af[4], bf[4];
#pragma unroll
        for (int i = 0; i < 4; ++i)
            af[i] = *(const f16x8*)(As + (wm + i * 16 + fr) * 32 + fk);
#pragma unroll
        for (int j = 0; j < 4; ++j)
            bf[j] = *(const f16x8*)(Bs + (wn + j * 16 + fr) * 32 + fk);
#pragma unroll
        for (int i = 0; i < 4; ++i)
#pragma unroll
            for (int j = 0; j < 4; ++j)
                acc[i][j] = __builtin_amdgcn_mfma_f32_16x16x32_f16(
                    af[i], bf[j], acc[i][j], 0, 0, 0);
        __syncthreads();
    }
    const int cr = (ln >> 4) * 4;
    const int cc = ln & 15;
#pragma unroll
    for (int i = 0; i < 4; ++i)
#pragma unroll
        for (int j = 0; j < 4; ++j) {
            const int row = m0 + wm + i * 16 + cr;
            const int col = n0 + wn + j * 16 + cc;
            float* cp = Cc + (size_t)row * 256 + col;
            const float bb = bias[col];
#pragma unroll
            for (int r = 0; r < 4; ++r) cp[(size_t)r * 256] = acc[i][j][r] + bb;
        }
}

// ---------------------------------------------------------------------------
extern "C" void kernel_launch(void* const* d_in, const int* in_sizes, int n_in,
                              void* d_out, int out_size, void* d_ws, size_t ws_size,
                              hipStream_t stream)
{
    const float* x     = (const float*)d_in[0];
    const float* rel   = (const float*)d_in[1];
    const float* qkv_w = (const float*)d_in[2];
    const float* qg    = (const float*)d_in[3];
    const float* kg    = (const float*)d_in[4];
    const float* pw    = (const float*)d_in[5];
    const float* pb    = (const float*)d_in[6];
    float* out = (float*)d_out;
    char* wsb = (char*)d_ws;

    float*    kvb   = (float*)wsb;                            // 8 MB
    _Float16* Qg    = (_Float16*)(wsb + ((size_t)8  << 20));  // 16 MB
    _Float16* Kg    = (_Float16*)(wsb + ((size_t)24 << 20));  // 16 MB
    _Float16* Vtg   = (_Float16*)(wsb + ((size_t)40 << 20));  // 16 MB
    _Float16* attnp = (_Float16*)(wsb + ((size_t)56 << 20));  // 16 MB
    _Float16* hb    = (_Float16*)(wsb + ((size_t)72 << 20));  // 16 MB
    _Float16* qwb   = (_Float16*)(wsb + ((size_t)88 << 20));  // 384 KB
    _Float16* pwb   = (_Float16*)(wsb + ((size_t)89 << 20));  // 128 KB

    k_prep<<<4352, 256, 0, stream>>>(x, rel, qkv_w, pw, hb, qwb, pwb);
    k_qkv_gemm<<<1536, 256, 0, stream>>>(hb, qwb, qg, kg, Qg, Kg, Vtg);
    k_chunk_kv<<<2048, 64, 0, stream>>>(Kg, Vtg, kvb);
    k_scan<<<64, 256, 0, stream>>>(kvb);
    k_attn<<<2048, 256, 0, stream>>>(Qg, Kg, Vtg, kvb, attnp);
    k_proj_gemm<<<512, 256, 0, stream>>>(attnp, pwb, pb, out);
}